// Round 6
// baseline (252.930 us; speedup 1.0000x reference)
//
#include <hip/hip_runtime.h>
#include <hip/hip_bf16.h>

#define SEQ 1024
#define DIM 128
#define NEG_SLOPE 0.1f

typedef __bf16 bf16x8 __attribute__((ext_vector_type(8)));
typedef float f32x4v __attribute__((ext_vector_type(4)));
typedef unsigned char uchar;

// d_ws layout: ntq fp8 [b][d][o] (4 MB), then Wt, Bt bf16 [d][k]
#define NTQ_BYTES ((size_t)32 * 128 * 1024)

__device__ __forceinline__ unsigned short bfb(float f) {
    __bf16 h = (__bf16)f;
    return __builtin_bit_cast(unsigned short, h);
}

// f32 -> e4m3fn RNE
__device__ __forceinline__ uchar f32_to_e4m3(float f) {
#if __has_builtin(__builtin_amdgcn_cvt_pk_fp8_f32)
    int r = __builtin_amdgcn_cvt_pk_fp8_f32(f, f, 0, false);
    return (uchar)(r & 0xff);
#else
    unsigned u = __builtin_bit_cast(unsigned, f);
    unsigned s = (u >> 24) & 0x80;
    int e = (u >> 23) & 0xff;
    unsigned m = u & 0x7fffff;
    int te = e - 120;
    if (te >= 1) {
        unsigned keep = m >> 20, rest = m & 0xfffff;
        keep += (rest > 0x80000u) || (rest == 0x80000u && (keep & 1));
        if (keep == 8) { keep = 0; ++te; }
        if (te > 15) return (uchar)(s | 0x7e);
        return (uchar)(s | (te << 3) | keep);
    }
    float af = f < 0 ? -f : f;
    int q = (int)(af * 512.0f + 0.5f);
    if (q > 7) q = 7;
    return (uchar)(s | q);
#endif
}

__device__ __forceinline__ long mk64(unsigned lo, unsigned hi) {
    return (long)(((unsigned long long)hi << 32) | lo);
}

// ---- pre-kernel 1: nodes[b][o][d] f32 -> ntq[b][d][o] fp8 e4m3 ----
__global__ __launch_bounds__(256)
void transpose_nodes(const float* __restrict__ nodes, uchar* __restrict__ nq)
{
    __shared__ float lds[64][33];
    const int b  = blockIdx.x >> 6;
    const int ot = (blockIdx.x >> 2) & 15;
    const int dt = blockIdx.x & 3;
    const int o0 = ot << 6, d0 = dt << 5;
    const int t  = threadIdx.x;

    const float* src = nodes + ((size_t)(b * SEQ + o0)) * DIM + d0;
    #pragma unroll
    for (int p = 0; p < 8; ++p) {
        const int o = (t >> 5) + p * 8;
        const int d = t & 31;
        lds[o][d] = src[(size_t)o * DIM + d];
    }
    __syncthreads();

    const int d_loc = t >> 3;
    const int p0    = (t & 7) * 8;
    union { uchar b[8]; uint2 u; } pk;
    #pragma unroll
    for (int j = 0; j < 8; ++j) pk.b[j] = f32_to_e4m3(lds[p0 + j][d_loc]);
    *(uint2*)(nq + ((size_t)(b * DIM + d0 + d_loc)) * SEQ + o0 + p0) = pk.u;
}

// ---- pre-kernel 2: W,B [k][d] f32 -> Wt,Bt [d][k] bf16 ----
__global__ __launch_bounds__(256)
void transpose_wb(const float* __restrict__ W, const float* __restrict__ Bm,
                  unsigned short* __restrict__ wt, unsigned short* __restrict__ bt)
{
    const int which = blockIdx.x & 1;
    const int slice = blockIdx.x >> 1;
    const float* in = which ? Bm : W;
    unsigned short* out = which ? bt : wt;
    const int base = slice * 1024;
    #pragma unroll
    for (int r = 0; r < 4; ++r) {
        const int idx = base + r * 256 + threadIdx.x;
        const int d = idx >> 7, k = idx & 127;
        out[idx] = bfb(in[k * DIM + d]);
    }
}

// ---- main fused kernel ----
// tile 32(i) x 128(d), grid 1024 = 4 blocks/CU.
// Phase A: barrier-free streaming transpose of this block's FULL adj i-slice
//          (1024 o x 32 i, 128 KB) into LDS fp8 (33 KB). Memcpy-like.
// Phase B: barrier-free MFMA K-loop, A from LDS, B from L2-hot ntq.
__global__ __launch_bounds__(256, 4)
void gcn_main(const float* __restrict__ nodes,
              const int* __restrict__ adj,
              const uchar* __restrict__ nq,
              const unsigned short* __restrict__ wt,
              const unsigned short* __restrict__ bt,
              float* __restrict__ out)
{
    union U {
        uchar maskT[32][1040];            // [i][o] fp8, stride 1040 = 65*16
        unsigned short pooled[32][136];   // [i][d] bf16 bits, stride 272 = 17*16
    };
    __shared__ __align__(16) U u;

    const int bid   = blockIdx.x;
    const int xcd   = bid & 7;
    const int slot  = bid >> 3;
    const int batch = ((slot >> 5) << 3) | xcd;   // all 32 i-tiles of a batch on one XCD
    const int itile = slot & 31;
    const int i0    = itile << 5;

    const int tid  = threadIdx.x;
    const int wave = tid >> 6;
    const int lane = tid & 63;
    const int wh   = wave >> 1;   // i-half (16 rows)
    const int wn   = wave & 1;    // d-half (64 cols)
    const int lrow = lane & 15;
    const int quad = lane >> 4;

    const int*   __restrict__ adj_b   = adj   + (size_t)batch * SEQ * SEQ;
    const uchar* __restrict__ nq_b    = nq    + (size_t)batch * DIM * SEQ;
    const float* __restrict__ nodes_b = nodes + (size_t)batch * SEQ * DIM;

    // ---- Phase A: adj[o][i0..i0+32) -> maskT[i][o], no barriers ----
    // thread: cg = col group (4 i, one int4), rg = row group (4 o). 128 rows/pass, 8 passes.
    const int cg = tid & 7;
    const int rg = tid >> 3;
    const int* pa_base = adj_b + (size_t)(rg * 4) * SEQ + i0 + cg * 4;

    int4 Acur[4], Anxt[4];
    #pragma unroll
    for (int r = 0; r < 4; ++r) Acur[r] = *(const int4*)(pa_base + (size_t)r * SEQ);

    #pragma unroll
    for (int p = 0; p < 8; ++p) {
        if (p < 7) {
            const int* pa = pa_base + (size_t)(p + 1) * 128 * SEQ;
            #pragma unroll
            for (int r = 0; r < 4; ++r) Anxt[r] = *(const int4*)(pa + (size_t)r * SEQ);
        }
        const int obase = p * 128 + rg * 4;
        #pragma unroll
        for (int c = 0; c < 4; ++c) {
            unsigned w = 0;
            w |= (((const int*)&Acur[0])[c] != 0 ? 0x38u : 0u);
            w |= (((const int*)&Acur[1])[c] != 0 ? 0x38u : 0u) << 8;
            w |= (((const int*)&Acur[2])[c] != 0 ? 0x38u : 0u) << 16;
            w |= (((const int*)&Acur[3])[c] != 0 ? 0x38u : 0u) << 24;
            *(unsigned*)&u.maskT[cg * 4 + c][obase] = w;
        }
        #pragma unroll
        for (int r = 0; r < 4; ++r) Acur[r] = Anxt[r];
    }
    __syncthreads();

    // ---- Phase B: K-loop, no barriers ----
    f32x4v acc[4] = {};
    f32x4v acc_cnt = {};
    const long ones = 0x3838383838383838L;   // 8x e4m3 1.0

    const uchar* pb0 = nq_b + (size_t)(wn * 64 + lrow) * SEQ + quad * 16;
    const uchar* prow = &u.maskT[wh * 16 + lrow][quad * 16];

    uint4 Bbuf[2][4];
    #pragma unroll
    for (int nf = 0; nf < 4; ++nf)
        Bbuf[0][nf] = *(const uint4*)(pb0 + (size_t)nf * 16 * SEQ);

    #pragma unroll
    for (int n = 0; n < 16; ++n) {
        if (n < 15) {
            #pragma unroll
            for (int nf = 0; nf < 4; ++nf)
                Bbuf[(n + 1) & 1][nf] = *(const uint4*)(pb0 + (size_t)nf * 16 * SEQ + (n + 1) * 64);
        }
        const uint4 a4 = *(const uint4*)(prow + n * 64);
        const uint4* Bc = Bbuf[n & 1];
        #pragma unroll
        for (int half = 0; half < 2; ++half) {
            const long a64 = half ? mk64(a4.z, a4.w) : mk64(a4.x, a4.y);
            #pragma unroll
            for (int nf = 0; nf < 4; ++nf) {
                const long b64 = half ? mk64(Bc[nf].z, Bc[nf].w) : mk64(Bc[nf].x, Bc[nf].y);
                acc[nf] = __builtin_amdgcn_mfma_f32_16x16x32_fp8_fp8(a64, b64, acc[nf], 0, 0, 0);
            }
            acc_cnt = __builtin_amdgcn_mfma_f32_16x16x32_fp8_fp8(a64, ones, acc_cnt, 0, 0, 0);
        }
    }

    // all waves done reading maskT before pooled overwrites it (union)
    __syncthreads();

    // poolsum -> pooled (divide by exact MFMA in-degree), C-layout -> A-layout via LDS
    #pragma unroll
    for (int r = 0; r < 4; ++r) {
        const int row = wh * 16 + quad * 4 + r;
        const float cnt = acc_cnt[r];
        const float inv = (cnt > 0.5f) ? 1.0f / cnt : 0.0f;
        #pragma unroll
        for (int nf = 0; nf < 4; ++nf) {
            const int col = wn * 64 + nf * 16 + lrow;
            u.pooled[row][col] = bfb(acc[nf][r] * inv);
        }
    }
    __syncthreads();

    f32x4v acc2[4] = {};
    const int d_b0 = wn * 64 + lrow;

    // pooled @ W + nodes @ B  (K=128, bf16)
    #pragma unroll
    for (int ks = 0; ks < 4; ++ks) {
        const int k0 = ks * 32 + quad * 8;
        bf16x8 av, av2, bw[4], bb[4];
        av = *(const bf16x8*)&u.pooled[wh * 16 + lrow][k0];
        {
            const float* p = nodes_b + (size_t)(i0 + wh * 16 + lrow) * DIM + k0;
            const float4 f1 = *(const float4*)p;
            const float4 f2 = *(const float4*)(p + 4);
            av2[0] = (__bf16)f1.x; av2[1] = (__bf16)f1.y;
            av2[2] = (__bf16)f1.z; av2[3] = (__bf16)f1.w;
            av2[4] = (__bf16)f2.x; av2[5] = (__bf16)f2.y;
            av2[6] = (__bf16)f2.z; av2[7] = (__bf16)f2.w;
        }
        #pragma unroll
        for (int nf = 0; nf < 4; ++nf) {
            bw[nf] = *(const bf16x8*)(wt + (size_t)(d_b0 + nf * 16) * DIM + k0);
            bb[nf] = *(const bf16x8*)(bt + (size_t)(d_b0 + nf * 16) * DIM + k0);
        }
        #pragma unroll
        for (int nf = 0; nf < 4; ++nf) {
            acc2[nf] = __builtin_amdgcn_mfma_f32_16x16x32_bf16(av,  bw[nf], acc2[nf], 0, 0, 0);
            acc2[nf] = __builtin_amdgcn_mfma_f32_16x16x32_bf16(av2, bb[nf], acc2[nf], 0, 0, 0);
        }
    }

    // leaky-relu + store
    float* out_b = out + (size_t)batch * SEQ * DIM;
    #pragma unroll
    for (int nf = 0; nf < 4; ++nf) {
        const int col = wn * 64 + nf * 16 + lrow;
        #pragma unroll
        for (int r = 0; r < 4; ++r) {
            const int row = i0 + wh * 16 + quad * 4 + r;
            const float x = acc2[nf][r];
            out_b[(size_t)row * DIM + col] = (x > 0.0f) ? x : NEG_SLOPE * x;
        }
    }
}

extern "C" void kernel_launch(void* const* d_in, const int* in_sizes, int n_in,
                              void* d_out, int out_size, void* d_ws, size_t ws_size,
                              hipStream_t stream) {
    const float* nodes = (const float*)d_in[0];
    const int*   adj   = (const int*)d_in[1];
    const float* W     = (const float*)d_in[2];
    const float* Bm    = (const float*)d_in[3];
    float*       out   = (float*)d_out;

    uchar* nq = (uchar*)d_ws;
    unsigned short* wt = (unsigned short*)(nq + NTQ_BYTES);
    unsigned short* bt = wt + 16384;

    transpose_nodes<<<dim3(2048), dim3(256), 0, stream>>>(nodes, nq);
    transpose_wb   <<<dim3(32),   dim3(256), 0, stream>>>(W, Bm, wt, bt);
    gcn_main       <<<dim3(1024), dim3(256), 0, stream>>>(nodes, adj, nq, wt, bt, out);
}